// Round 2
// baseline (877.459 us; speedup 1.0000x reference)
//
#include <hip/hip_runtime.h>

#define D 256
#define KCODES 8192
#define NTOK 16384
#define QSIZE (NTOK * D)
#define NBLK 128              // screening blocks of 64 codes
#define CBS 64
// TH: candidate window. Budget (fp16 screen, cb pre-scaled 2^12 so no fp16
// subnormals): ref-rounding eta <= 3.05e-5 + 2*fp16-dot err (max-stat) ~2.4e-5
// + bf16 bmin quantization ~4e-6  => delta ~5.9e-5, need TH >= 2*delta ~1.2e-4.
// TH = 2e-4 gives ~1.7x margin. (Validated: R11 first-call passed bit-exact.)
#define TH 2e-4f
#define CBSCALE 4096.0f       // exact pow2; acc = 2^12 * dot
#define UNSCALE2 4.8828125e-4f // 2^-11 = 2 * 2^-12 (exact)
#define CCAP 4096             // per-nb candidate capacity (stat need ~170-1100)

typedef _Float16 f16x8 __attribute__((ext_vector_type(8)));  // 8 fp16, 4 VGPRs
typedef float f32x4 __attribute__((ext_vector_type(4)));
typedef __attribute__((address_space(3))) void* lds_vp;
typedef __attribute__((address_space(1))) const void* gbl_vp;

// pass2b LDS: cb^T fp32 [256][65] (66560 B) + per-wave x rows [4w][4r][256] (16384 B)
#define P2_LDS (256 * 65 * 4 + 16 * 256 * 4)

__device__ __forceinline__ ushort f32_to_bf16(float f) {
    unsigned u = __float_as_uint(f);
    return (ushort)((u + 0x7FFFu + ((u >> 16) & 1)) >> 16);
}
__device__ __forceinline__ ushort f32_to_f16(float f) {
    _Float16 h = (_Float16)f;          // v_cvt_f16_f32, RNE
    ushort u; __builtin_memcpy(&u, &h, 2);
    return u;
}

// ---- fused: x -> fp16 + row ||x||^2 (wave w of block b owns row b*4+w) ----
__global__ __launch_bounds__(256) void cvtx_kernel(const float* __restrict__ x,
                                                   ushort* __restrict__ xb,
                                                   float* __restrict__ xsq) {
    int i = blockIdx.x * 256 + threadIdx.x;      // float4 index
    float4 v = reinterpret_cast<const float4*>(x)[i];
    ushort4 o;
    o.x = f32_to_f16(v.x); o.y = f32_to_f16(v.y);
    o.z = f32_to_f16(v.z); o.w = f32_to_f16(v.w);
    reinterpret_cast<ushort4*>(xb)[i] = o;
    float s = v.x * v.x + v.y * v.y + v.z * v.z + v.w * v.w;
#pragma unroll
    for (int off = 32; off > 0; off >>= 1) s += __shfl_down(s, off);
    if ((threadIdx.x & 63) == 0) xsq[i >> 6] = s;
}

// ---- fused: cb -> scaled fp16 + row ||e||^2 (e2 from UNscaled values) ----
__global__ __launch_bounds__(256) void cvtc_kernel(const float* __restrict__ cb,
                                                   ushort* __restrict__ cbb,
                                                   float* __restrict__ e2) {
    int i = blockIdx.x * 256 + threadIdx.x;
    float4 v = reinterpret_cast<const float4*>(cb)[i];
    ushort4 o;
    o.x = f32_to_f16(v.x * CBSCALE); o.y = f32_to_f16(v.y * CBSCALE);
    o.z = f32_to_f16(v.z * CBSCALE); o.w = f32_to_f16(v.w * CBSCALE);
    reinterpret_cast<ushort4*>(cbb)[i] = o;
    float s = v.x * v.x + v.y * v.y + v.z * v.z + v.w * v.w;
#pragma unroll
    for (int off = 32; off > 0; off >>= 1) s += __shfl_down(s, off);
    if ((threadIdx.x & 63) == 0) e2[i >> 6] = s;
}

// ---- Pass 1: fp16 MFMA screening GEMM, 2-phase double-buffered staging ----
// BK=32 K-loop, global_load_lds width-16 into linear [2][128][32] fp16 tiles,
// stage(kt+1) issued BEFORE compute(kt); one __syncthreads (vmcnt0+barrier)
// per K-step. MFMA sequence (8 chained 16x16x32 ascending kt, identical
// fragments) is bit-identical to R1 -> bmin bits unchanged.
__global__ __launch_bounds__(256, 3) void pass1_kernel(
    const ushort* __restrict__ xb, const ushort* __restrict__ cbb,
    const float* __restrict__ e2, ushort* __restrict__ bmin) {
    __shared__ ushort ash[2][128 * 32];
    __shared__ ushort bsh[2][128 * 32];
    const int tid = threadIdx.x;
    const int w = tid >> 6, l = tid & 63;
    const int wr = w >> 1, wc = w & 1;
    const int t0 = blockIdx.x * 128, n0 = blockIdx.y * 128;

    f32x4 acc[4][4];
#pragma unroll
    for (int mt = 0; mt < 4; ++mt)
#pragma unroll
        for (int nt = 0; nt < 4; ++nt) acc[mt][nt] = (f32x4)0.f;

    // Wave w stages LDS bytes [w*2048, (w+1)*2048) of each 8 KB tile via two
    // 1 KB wave-loads; HW writes lds_base + lane*16 (linear [128][32] fp16).
    const int byte0 = w * 2048 + l * 16;
    const int row0 = byte0 >> 6, c80 = (byte0 >> 4) & 3;
    const int byte1 = byte0 + 1024;
    const int row1 = byte1 >> 6, c81 = (byte1 >> 4) & 3;
    const ushort* ga0 = xb + (size_t)(t0 + row0) * D + c80 * 8;
    const ushort* ga1 = xb + (size_t)(t0 + row1) * D + c81 * 8;
    const ushort* gb0 = cbb + (size_t)(n0 + row0) * D + c80 * 8;
    const ushort* gb1 = cbb + (size_t)(n0 + row1) * D + c81 * 8;

#define STAGE(KT, BUF)                                                                     \
    do {                                                                                   \
        __builtin_amdgcn_global_load_lds((gbl_vp)(ga0 + (KT) * 32),                        \
                                         (lds_vp)(&ash[BUF][w * 1024]), 16, 0, 0);         \
        __builtin_amdgcn_global_load_lds((gbl_vp)(ga1 + (KT) * 32),                        \
                                         (lds_vp)(&ash[BUF][w * 1024 + 512]), 16, 0, 0);   \
        __builtin_amdgcn_global_load_lds((gbl_vp)(gb0 + (KT) * 32),                        \
                                         (lds_vp)(&bsh[BUF][w * 1024]), 16, 0, 0);         \
        __builtin_amdgcn_global_load_lds((gbl_vp)(gb1 + (KT) * 32),                        \
                                         (lds_vp)(&bsh[BUF][w * 1024 + 512]), 16, 0, 0);   \
    } while (0)

    STAGE(0, 0);
    __syncthreads();                    // drains vmcnt(0): buf0 ready
#pragma unroll
    for (int kt = 0; kt < 8; ++kt) {
        const int cur = kt & 1;
        if (kt < 7) STAGE(kt + 1, cur ^ 1);   // prefetch overlaps this MFMA phase
        const ushort* xbase = &ash[cur][0] + (wr * 64 + (l & 15)) * 32 + (l >> 4) * 8;
        const ushort* cbase = &bsh[cur][0] + (wc * 64 + (l & 15)) * 32 + (l >> 4) * 8;
        f16x8 a[4], b[4];
#pragma unroll
        for (int mt = 0; mt < 4; ++mt)
            a[mt] = *reinterpret_cast<const f16x8*>(xbase + mt * 16 * 32);
#pragma unroll
        for (int nt = 0; nt < 4; ++nt)
            b[nt] = *reinterpret_cast<const f16x8*>(cbase + nt * 16 * 32);
#pragma unroll
        for (int mt = 0; mt < 4; ++mt)
#pragma unroll
            for (int nt = 0; nt < 4; ++nt)
                acc[mt][nt] = __builtin_amdgcn_mfma_f32_16x16x32_f16(
                    a[mt], b[nt], acc[mt][nt], 0, 0, 0);
        __syncthreads();                // next buf's loads drained + reuse-safe
    }
#undef STAGE

    float e2v[4];
#pragma unroll
    for (int nt = 0; nt < 4; ++nt)
        e2v[nt] = e2[n0 + wc * 64 + nt * 16 + (l & 15)];
    const int nb64 = blockIdx.y * 2 + wc;
#pragma unroll
    for (int mt = 0; mt < 4; ++mt) {
#pragma unroll
        for (int r = 0; r < 4; ++r) {
            float dm = fmaf(-UNSCALE2, acc[mt][0][r], e2v[0]);
#pragma unroll
            for (int nt = 1; nt < 4; ++nt)
                dm = fminf(dm, fmaf(-UNSCALE2, acc[mt][nt][r], e2v[nt]));
#pragma unroll
            for (int off = 1; off < 16; off <<= 1)
                dm = fminf(dm, __shfl_xor(dm, off));
            if ((l & 15) == 0) {
                int token = t0 + wr * 64 + mt * 16 + (l >> 4) * 4 + r;
                bmin[(size_t)token * NBLK + nb64] = f32_to_bf16(dm);
            }
        }
    }
}

// ---- Pass 2a: per-token min over 128 bf16 block-mins; init bestKey; fold
// the TH flag-test, appending token to per-nb candidate lists. Also copies
// e2/xsq into d_out scratch (pass2b reads only device-proven buffers) and
// zeroes the loss accumulator. Candidate set identical to prior rounds.
__global__ __launch_bounds__(256) void pass2a_kernel(
    const ushort* __restrict__ bmin, unsigned long long* __restrict__ bestKey,
    unsigned* __restrict__ cand, unsigned* __restrict__ counts,
    const float* __restrict__ e2, const float* __restrict__ xsq,
    float* __restrict__ e2d, float* __restrict__ xsqd, float* __restrict__ out) {
    int t = blockIdx.x * 256 + threadIdx.x;
    const uint4* bm = reinterpret_cast<const uint4*>(bmin + (size_t)t * NBLK);
    uint4 vv[16];
#pragma unroll
    for (int i = 0; i < 16; ++i) vv[i] = bm[i];
    float m = 3.4e38f;
#pragma unroll
    for (int i = 0; i < 16; ++i) {
        unsigned a[4] = {vv[i].x, vv[i].y, vv[i].z, vv[i].w};
#pragma unroll
        for (int j = 0; j < 4; ++j) {
            m = fminf(m, __uint_as_float(a[j] << 16));
            m = fminf(m, __uint_as_float(a[j] & 0xFFFF0000u));
        }
    }
    bestKey[t] = 0xFFFFFFFFFFFFFFFFULL;
    xsqd[t] = xsq[t];
    if (t < KCODES) e2d[t] = e2[t];
    if (t == 0) out[(size_t)QSIZE + NTOK] = 0.f;
    const float thr = m + TH;
#pragma unroll
    for (int i = 0; i < 16; ++i) {
        unsigned a[4] = {vv[i].x, vv[i].y, vv[i].z, vv[i].w};
#pragma unroll
        for (int j = 0; j < 4; ++j) {
            float lo = __uint_as_float(a[j] << 16);            // nb = 8i+2j
            float hi = __uint_as_float(a[j] & 0xFFFF0000u);    // nb = 8i+2j+1
            int nb = i * 8 + j * 2;
            if (lo <= thr) {
                unsigned s = atomicAdd(&counts[nb], 1u);
                if (s < CCAP) cand[(size_t)nb * CCAP + s] = (unsigned)t;
            }
            if (hi <= thr) {
                unsigned s = atomicAdd(&counts[nb + 1], 1u);
                if (s < CCAP) cand[(size_t)(nb + 1) * CCAP + s] = (unsigned)t;
            }
        }
    }
}

// ---- Pass 2b: exact fp32-chain rescan of compacted candidates ----
// NUMERICS: identical chain — single sequential fma k=0..255 per (token,
// code), d = fl(fl(xsq+e2) - 2*dot), shfl-xor tie-break (smallest index),
// packed-key atomicMin. Changes vs R1 (control flow / data movement only):
//   * x[t][k] broadcast now via per-wave-private LDS rows (fp32 roundtrip,
//     lossless; broadcast ds_read_b128, conflict-free) — NO v_readlane, no
//     VGPR->SGPR hazard chains. Same values, same fma order.
//   * dense grid: 256 blocks = 2 per nb, waves stride the candidate list;
//     next group's x rows + xsq prefetched during current chain (T14).
//   * e2/xsq read from d_out copies (e2d/xsqd).
__global__ __launch_bounds__(256, 1) void pass2b_kernel(
    const float* __restrict__ x, const float* __restrict__ cb,
    const float* __restrict__ e2d, const float* __restrict__ xsqd,
    const unsigned* __restrict__ cand, const unsigned* __restrict__ counts,
    unsigned long long* __restrict__ bestKey) {
    extern __shared__ float csh[];          // [256][65] cb^T + [16][256] x rows
    const int tid = threadIdx.x;
    const int nb = blockIdx.x >> 1;         // 64-code block
    const int half = blockIdx.x & 1;
    int cnt = (int)counts[nb];
    if (cnt > CCAP) cnt = CCAP;
    if (cnt == 0) return;

    // stage 64 cb rows transposed (coalesced reads; 8-way writes, one-time)
#pragma unroll
    for (int r = 0; r < 16; ++r) {
        int i = r * 256 + tid;
        int row = i >> 6, kq = i & 63;
        float4 v = reinterpret_cast<const float4*>(cb + (size_t)(nb * CBS + row) * D)[kq];
        csh[(kq * 4 + 0) * 65 + row] = v.x;
        csh[(kq * 4 + 1) * 65 + row] = v.y;
        csh[(kq * 4 + 2) * 65 + row] = v.z;
        csh[(kq * 4 + 3) * 65 + row] = v.w;
    }
    __syncthreads();                        // last barrier in this kernel

    const int w = tid >> 6, j = tid & 63;
    float* xsh = csh + 256 * 65 + w * 1024; // this wave's [4][256] x rows
    const float e2v = e2d[nb * CBS + j];
    const int ci0 = nb * CBS + j;
    const float4* X4 = reinterpret_cast<const float4*>(x);
    const unsigned* clist = cand + (size_t)nb * CCAP;
    const int slot = half * 4 + w;          // 0..7 sweep slots per nb
    const int p0 = slot * 4;
    if (p0 >= cnt) return;                  // wave-uniform; no barriers follow

    int t[4]; float4 vx[4]; float xs[4];
#pragma unroll
    for (int g = 0; g < 4; ++g) {
        int idx = p0 + g < cnt ? p0 + g : cnt - 1;   // tail-replicate (idempotent)
        t[g] = (int)clist[idx];
        vx[g] = X4[(size_t)t[g] * 64 + j];
        xs[g] = xsqd[t[g]];
    }
    for (int p = p0; p < cnt; p += 32) {
        // write current group's x rows (wave-private; in-order LDS per wave)
#pragma unroll
        for (int g = 0; g < 4; ++g)
            *reinterpret_cast<float4*>(xsh + g * 256 + j * 4) = vx[g];
        const int pn = p + 32;
        int tn[4] = {0, 0, 0, 0}; float4 vn[4]; float sn[4] = {0, 0, 0, 0};
        if (pn < cnt) {                      // prefetch next group (latency hides
#pragma unroll
            for (int g = 0; g < 4; ++g) {    //  under the 64-iter chain below)
                int idx = pn + g < cnt ? pn + g : cnt - 1;
                tn[g] = (int)clist[idx];
                vn[g] = X4[(size_t)tn[g] * 64 + j];
                sn[g] = xsqd[tn[g]];
            }
        }
        float a0 = 0.f, a1 = 0.f, a2 = 0.f, a3 = 0.f;
        // k ascending, ONE fma chain per (token, code) — bit-compat order.
        // x broadcast: same-address ds_read_b128 (conflict-free, no hazards).
#pragma unroll
        for (int kq = 0; kq < 64; ++kq) {
            float4 x0 = *reinterpret_cast<const float4*>(xsh + 0 * 256 + kq * 4);
            float4 x1 = *reinterpret_cast<const float4*>(xsh + 1 * 256 + kq * 4);
            float4 x2 = *reinterpret_cast<const float4*>(xsh + 2 * 256 + kq * 4);
            float4 x3 = *reinterpret_cast<const float4*>(xsh + 3 * 256 + kq * 4);
            float c0 = csh[(kq * 4 + 0) * 65 + j];
            float c1 = csh[(kq * 4 + 1) * 65 + j];
            float c2 = csh[(kq * 4 + 2) * 65 + j];
            float c3 = csh[(kq * 4 + 3) * 65 + j];
            a0 = fmaf(x0.x, c0, a0); a0 = fmaf(x0.y, c1, a0);
            a0 = fmaf(x0.z, c2, a0); a0 = fmaf(x0.w, c3, a0);
            a1 = fmaf(x1.x, c0, a1); a1 = fmaf(x1.y, c1, a1);
            a1 = fmaf(x1.z, c2, a1); a1 = fmaf(x1.w, c3, a1);
            a2 = fmaf(x2.x, c0, a2); a2 = fmaf(x2.y, c1, a2);
            a2 = fmaf(x2.z, c2, a2); a2 = fmaf(x2.w, c3, a2);
            a3 = fmaf(x3.x, c0, a3); a3 = fmaf(x3.y, c1, a3);
            a3 = fmaf(x3.z, c2, a3); a3 = fmaf(x3.w, c3, a3);
        }
        float av[4] = {a0, a1, a2, a3};
#pragma unroll
        for (int g = 0; g < 4; ++g) {
            float dd = fmaf(-2.f, av[g], xs[g] + e2v);
            int ci = ci0;
#pragma unroll
            for (int off = 1; off < 64; off <<= 1) {
                float od = __shfl_xor(dd, off);
                int oc = __shfl_xor(ci, off);
                if (od < dd || (od == dd && oc < ci)) { dd = od; ci = oc; }
            }
            if (j == 0) {
                unsigned u = __float_as_uint(dd);
                u = (u & 0x80000000u) ? ~u : (u | 0x80000000u);
                unsigned long long key =
                    ((unsigned long long)u << 32) | (unsigned)ci;
                atomicMin(bestKey + t[g], key);   // non-returning: no stall
            }
        }
        if (pn < cnt) {
#pragma unroll
            for (int g = 0; g < 4; ++g) { t[g] = tn[g]; vx[g] = vn[g]; xs[g] = sn[g]; }
        }
    }
}

// ---- Pass 3: gather codebook row, emit quantized + idx + partial loss ----
__global__ __launch_bounds__(256) void gather_kernel(
    const float* __restrict__ x, const float* __restrict__ cb,
    const unsigned long long* __restrict__ bestKey,
    float* __restrict__ out, float* __restrict__ partial) {
    __shared__ float red[4];
    const int token = blockIdx.x;
    const int tid = threadIdx.x;
    int idx = (int)(bestKey[token] & 0xFFFFFFFFULL);
    if ((unsigned)idx >= (unsigned)KCODES) idx = 0;  // defensive: no OOB access
    float q = cb[(size_t)idx * D + tid];
    float xv = x[(size_t)token * D + tid];
    out[(size_t)token * D + tid] = q;
    float d = q - xv;
    d = d * d;
#pragma unroll
    for (int off = 32; off > 0; off >>= 1) d += __shfl_down(d, off);
    if ((tid & 63) == 0) red[tid >> 6] = d;
    __syncthreads();
    if (tid == 0) {
        partial[token] = red[0] + red[1] + red[2] + red[3];
        out[(size_t)QSIZE + token] = (float)idx;
    }
}

// 64 blocks, one element/thread; per-block reduce + one atomicAdd into the
// (pass2a-zeroed) loss slot. Scaled-per-block summation differs from the
// old single-block sum by ~1e-9 relative — far inside tolerance.
__global__ __launch_bounds__(256) void loss_kernel(const float* __restrict__ partial,
                                                   float* __restrict__ out) {
    __shared__ float red[4];
    int gid = blockIdx.x * 256 + threadIdx.x;
    float s = partial[gid];
#pragma unroll
    for (int off = 32; off > 0; off >>= 1) s += __shfl_down(s, off);
    if ((threadIdx.x & 63) == 0) red[threadIdx.x >> 6] = s;
    __syncthreads();
    if (threadIdx.x == 0) {
        float total = red[0] + red[1] + red[2] + red[3];
        atomicAdd(out + (size_t)QSIZE + NTOK, 0.25f * total / (float)QSIZE);
    }
}

extern "C" void kernel_launch(void* const* d_in, const int* in_sizes, int n_in,
                              void* d_out, int out_size, void* d_ws, size_t ws_size,
                              hipStream_t stream) {
    const float* x = (const float*)d_in[0];     // [16384, 256]
    const float* cb = (const float*)d_in[1];    // [8192, 256]
    float* out = (float*)d_out;
    float* ws = (float*)d_ws;

    // d_out scratch map (all regions dead before gather/loss overwrite them):
    //   [0, 8M):   xb fp16 (pass1 in) -> cand u32 [128][4096] (pass2a writes
    //              AFTER pass1 done; stream-ordered)
    //   [8M, 12M): bmin bf16 [NTOK][128]
    //   [12M,16M): cbb fp16 (pass1 in) -> e2d f32[8192] | xsqd f32[16384]
    //              (pass2a writes AFTER pass1)
    //   [16M, +512): counts u32[128] (inside idx region; dead before gather)
    //   loss slot out[QSIZE+NTOK]: zeroed by pass2a, atomicAdd'ed by loss
    ushort* xb = (ushort*)d_out;
    ushort* bmin = (ushort*)((char*)d_out + 8388608);
    ushort* cbb = (ushort*)((char*)d_out + 12582912);
    unsigned* cand = (unsigned*)d_out;
    float* e2d = (float*)((char*)d_out + 12582912);
    float* xsqd = e2d + KCODES;
    unsigned* counts = (unsigned*)((char*)d_out + 16777216);

    // ws (floats): e2[8192] | xsq[16384] | (spare) | partial[16384] | bestKey u64
    float* e2 = ws;
    float* xsq = ws + 8192;
    float* partial = ws + 8192 + 2 * 16384;
    unsigned long long* bestKey = (unsigned long long*)(ws + 8192 + 3 * 16384);

    hipFuncSetAttribute((const void*)pass2b_kernel,
                        hipFuncAttributeMaxDynamicSharedMemorySize, P2_LDS);

    cvtx_kernel<<<QSIZE / 1024, 256, 0, stream>>>(x, xb, xsq);
    cvtc_kernel<<<KCODES * D / 1024, 256, 0, stream>>>(cb, cbb, e2);
    pass1_kernel<<<dim3(NTOK / 128, KCODES / 128), 256, 0, stream>>>(xb, cbb, e2, bmin);
    hipMemsetAsync(counts, 0, NBLK * sizeof(unsigned), stream);
    pass2a_kernel<<<NTOK / 256, 256, 0, stream>>>(bmin, bestKey, cand, counts,
                                                  e2, xsq, e2d, xsqd, out);
    pass2b_kernel<<<2 * NBLK, 256, P2_LDS, stream>>>(
        x, cb, e2d, xsqd, cand, counts, bestKey);
    gather_kernel<<<NTOK, 256, 0, stream>>>(x, cb, bestKey, out, partial);
    loss_kernel<<<NTOK / 256, 256, 0, stream>>>(partial, out);
}

// Round 3
// 463.728 us; speedup vs baseline: 1.8922x; 1.8922x over previous
//
#include <hip/hip_runtime.h>

#define D 256
#define KCODES 8192
#define NTOK 16384
#define QSIZE (NTOK * D)
#define NBLK 128              // screening blocks of 64 codes
#define CBS 64
// TH: candidate window. Budget (fp16 screen, cb pre-scaled 2^12 so no fp16
// subnormals): ref-rounding eta <= 3.05e-5 + 2*fp16-dot err (max-stat) ~2.4e-5
// + bf16 bmin quantization ~4e-6  => delta ~5.9e-5, need TH >= 2*delta ~1.2e-4.
// TH = 2e-4 gives ~1.7x margin. (Validated: R11 first-call passed bit-exact.)
#define TH 2e-4f
#define CBSCALE 4096.0f       // exact pow2; acc = 2^12 * dot
#define UNSCALE2 4.8828125e-4f // 2^-11 = 2 * 2^-12 (exact)
#define CCAP 4096             // per-nb candidate capacity (stat need ~170-1100)

typedef _Float16 f16x8 __attribute__((ext_vector_type(8)));  // 8 fp16, 4 VGPRs
typedef float f32x4 __attribute__((ext_vector_type(4)));
typedef __attribute__((address_space(3))) void* lds_vp;
typedef __attribute__((address_space(1))) const void* gbl_vp;

#define P2_LDS (256 * 65 * 4)           // 66560 B: cb^T fp32 [256][65] ONLY

__device__ __forceinline__ ushort f32_to_bf16(float f) {
    unsigned u = __float_as_uint(f);
    return (ushort)((u + 0x7FFFu + ((u >> 16) & 1)) >> 16);
}
__device__ __forceinline__ ushort f32_to_f16(float f) {
    _Float16 h = (_Float16)f;          // v_cvt_f16_f32, RNE
    ushort u; __builtin_memcpy(&u, &h, 2);
    return u;
}
// race-free broadcast: v_readlane_b32 (register file, exec-independent)
__device__ __forceinline__ float rdlane(float v, int lane) {
    return __uint_as_float(__builtin_amdgcn_readlane(__float_as_uint(v), lane));
}

// ---- fused: x -> fp16 + row ||x||^2 (same values/order as old xsq) ----
__global__ __launch_bounds__(256) void cvtx_kernel(const float* __restrict__ x,
                                                   ushort* __restrict__ xb,
                                                   float* __restrict__ xsq) {
    int i = blockIdx.x * 256 + threadIdx.x;      // float4 index
    float4 v = reinterpret_cast<const float4*>(x)[i];
    ushort4 o;
    o.x = f32_to_f16(v.x); o.y = f32_to_f16(v.y);
    o.z = f32_to_f16(v.z); o.w = f32_to_f16(v.w);
    reinterpret_cast<ushort4*>(xb)[i] = o;
    float s = v.x * v.x + v.y * v.y + v.z * v.z + v.w * v.w;
#pragma unroll
    for (int off = 32; off > 0; off >>= 1) s += __shfl_down(s, off);
    if ((threadIdx.x & 63) == 0) xsq[i >> 6] = s;
}

// ---- fused: cb -> scaled fp16 + row ||e||^2 (e2 from UNscaled values) ----
__global__ __launch_bounds__(256) void cvtc_kernel(const float* __restrict__ cb,
                                                   ushort* __restrict__ cbb,
                                                   float* __restrict__ e2) {
    int i = blockIdx.x * 256 + threadIdx.x;
    float4 v = reinterpret_cast<const float4*>(cb)[i];
    ushort4 o;
    o.x = f32_to_f16(v.x * CBSCALE); o.y = f32_to_f16(v.y * CBSCALE);
    o.z = f32_to_f16(v.z * CBSCALE); o.w = f32_to_f16(v.w * CBSCALE);
    reinterpret_cast<ushort4*>(cbb)[i] = o;
    float s = v.x * v.x + v.y * v.y + v.z * v.z + v.w * v.w;
#pragma unroll
    for (int off = 32; off > 0; off >>= 1) s += __shfl_down(s, off);
    if ((threadIdx.x & 63) == 0) e2[i >> 6] = s;
}

// ---- Pass 1: fp16 MFMA screening GEMM, 2-phase double-buffered staging ----
// BK=32 K-loop, global_load_lds width-16 into linear [2][128][32] fp16 tiles,
// stage(kt+1) issued BEFORE compute(kt); one __syncthreads per K-step.
// MFMA sequence (8 chained 16x16x32 ascending kt, identical fragments) is
// bit-identical to prior rounds -> bmin bits unchanged. (Validated in R2.)
__global__ __launch_bounds__(256, 3) void pass1_kernel(
    const ushort* __restrict__ xb, const ushort* __restrict__ cbb,
    const float* __restrict__ e2, ushort* __restrict__ bmin) {
    __shared__ ushort ash[2][128 * 32];
    __shared__ ushort bsh[2][128 * 32];
    const int tid = threadIdx.x;
    const int w = tid >> 6, l = tid & 63;
    const int wr = w >> 1, wc = w & 1;
    const int t0 = blockIdx.x * 128, n0 = blockIdx.y * 128;

    f32x4 acc[4][4];
#pragma unroll
    for (int mt = 0; mt < 4; ++mt)
#pragma unroll
        for (int nt = 0; nt < 4; ++nt) acc[mt][nt] = (f32x4)0.f;

    const int byte0 = w * 2048 + l * 16;
    const int row0 = byte0 >> 6, c80 = (byte0 >> 4) & 3;
    const int byte1 = byte0 + 1024;
    const int row1 = byte1 >> 6, c81 = (byte1 >> 4) & 3;
    const ushort* ga0 = xb + (size_t)(t0 + row0) * D + c80 * 8;
    const ushort* ga1 = xb + (size_t)(t0 + row1) * D + c81 * 8;
    const ushort* gb0 = cbb + (size_t)(n0 + row0) * D + c80 * 8;
    const ushort* gb1 = cbb + (size_t)(n0 + row1) * D + c81 * 8;

#define STAGE(KT, BUF)                                                                     \
    do {                                                                                   \
        __builtin_amdgcn_global_load_lds((gbl_vp)(ga0 + (KT) * 32),                        \
                                         (lds_vp)(&ash[BUF][w * 1024]), 16, 0, 0);         \
        __builtin_amdgcn_global_load_lds((gbl_vp)(ga1 + (KT) * 32),                        \
                                         (lds_vp)(&ash[BUF][w * 1024 + 512]), 16, 0, 0);   \
        __builtin_amdgcn_global_load_lds((gbl_vp)(gb0 + (KT) * 32),                        \
                                         (lds_vp)(&bsh[BUF][w * 1024]), 16, 0, 0);         \
        __builtin_amdgcn_global_load_lds((gbl_vp)(gb1 + (KT) * 32),                        \
                                         (lds_vp)(&bsh[BUF][w * 1024 + 512]), 16, 0, 0);   \
    } while (0)

    STAGE(0, 0);
    __syncthreads();                    // drains vmcnt(0): buf0 ready
#pragma unroll
    for (int kt = 0; kt < 8; ++kt) {
        const int cur = kt & 1;
        if (kt < 7) STAGE(kt + 1, cur ^ 1);   // prefetch overlaps this MFMA phase
        const ushort* xbase = &ash[cur][0] + (wr * 64 + (l & 15)) * 32 + (l >> 4) * 8;
        const ushort* cbase = &bsh[cur][0] + (wc * 64 + (l & 15)) * 32 + (l >> 4) * 8;
        f16x8 a[4], b[4];
#pragma unroll
        for (int mt = 0; mt < 4; ++mt)
            a[mt] = *reinterpret_cast<const f16x8*>(xbase + mt * 16 * 32);
#pragma unroll
        for (int nt = 0; nt < 4; ++nt)
            b[nt] = *reinterpret_cast<const f16x8*>(cbase + nt * 16 * 32);
#pragma unroll
        for (int mt = 0; mt < 4; ++mt)
#pragma unroll
            for (int nt = 0; nt < 4; ++nt)
                acc[mt][nt] = __builtin_amdgcn_mfma_f32_16x16x32_f16(
                    a[mt], b[nt], acc[mt][nt], 0, 0, 0);
        __syncthreads();                // next buf's loads drained + reuse-safe
    }
#undef STAGE

    float e2v[4];
#pragma unroll
    for (int nt = 0; nt < 4; ++nt)
        e2v[nt] = e2[n0 + wc * 64 + nt * 16 + (l & 15)];
    const int nb64 = blockIdx.y * 2 + wc;
#pragma unroll
    for (int mt = 0; mt < 4; ++mt) {
#pragma unroll
        for (int r = 0; r < 4; ++r) {
            float dm = fmaf(-UNSCALE2, acc[mt][0][r], e2v[0]);
#pragma unroll
            for (int nt = 1; nt < 4; ++nt)
                dm = fminf(dm, fmaf(-UNSCALE2, acc[mt][nt][r], e2v[nt]));
#pragma unroll
            for (int off = 1; off < 16; off <<= 1)
                dm = fminf(dm, __shfl_xor(dm, off));
            if ((l & 15) == 0) {
                int token = t0 + wr * 64 + mt * 16 + (l >> 4) * 4 + r;
                bmin[(size_t)token * NBLK + nb64] = f32_to_bf16(dm);
            }
        }
    }
}

// ---- Pass 2a: per-token min over 128 bf16 block-mins; init bestKey; fold
// the TH flag-test, appending token to per-nb candidate lists; zero the loss
// accumulator. Candidate set identical to prior rounds. ----
__global__ __launch_bounds__(256) void pass2a_kernel(
    const ushort* __restrict__ bmin, unsigned long long* __restrict__ bestKey,
    unsigned* __restrict__ cand, unsigned* __restrict__ counts,
    float* __restrict__ out) {
    int t = blockIdx.x * 256 + threadIdx.x;
    const uint4* bm = reinterpret_cast<const uint4*>(bmin + (size_t)t * NBLK);
    uint4 vv[16];
#pragma unroll
    for (int i = 0; i < 16; ++i) vv[i] = bm[i];
    float m = 3.4e38f;
#pragma unroll
    for (int i = 0; i < 16; ++i) {
        unsigned a[4] = {vv[i].x, vv[i].y, vv[i].z, vv[i].w};
#pragma unroll
        for (int j = 0; j < 4; ++j) {
            m = fminf(m, __uint_as_float(a[j] << 16));
            m = fminf(m, __uint_as_float(a[j] & 0xFFFF0000u));
        }
    }
    bestKey[t] = 0xFFFFFFFFFFFFFFFFULL;
    if (t == 0) out[(size_t)QSIZE + NTOK] = 0.f;
    const float thr = m + TH;
#pragma unroll
    for (int i = 0; i < 16; ++i) {
        unsigned a[4] = {vv[i].x, vv[i].y, vv[i].z, vv[i].w};
#pragma unroll
        for (int j = 0; j < 4; ++j) {
            float lo = __uint_as_float(a[j] << 16);            // nb = 8i+2j
            float hi = __uint_as_float(a[j] & 0xFFFF0000u);    // nb = 8i+2j+1
            int nb = i * 8 + j * 2;
            if (lo <= thr) {
                unsigned s = atomicAdd(&counts[nb], 1u);
                if (s < CCAP) cand[(size_t)nb * CCAP + s] = (unsigned)t;
            }
            if (hi <= thr) {
                unsigned s = atomicAdd(&counts[nb + 1], 1u);
                if (s < CCAP) cand[(size_t)(nb + 1) * CCAP + s] = (unsigned)t;
            }
        }
    }
}

// ---- Pass 2b: exact fp32-chain rescan of compacted candidates ----
// NUMERICS: R1's inner loop VERBATIM (proven: VGPR 128, no spill, passed) —
// single sequential fma chain k=0..255 per (token, code), operand broadcast
// via v_readlane, d = fl(fl(xsq+e2) - 2*dot), shfl-xor tie-break (smallest
// index), packed-key atomicMin. ONLY change vs R1: dense grid — 512 blocks
// = 4 per nb (no mostly-empty 4096-block churn with 65 KB LDS allocs);
// 16 slot-strided slices of the candidate list per nb.
__global__ __launch_bounds__(256, 2) void pass2b_kernel(
    const float* __restrict__ x, const float* __restrict__ cb,
    const float* __restrict__ e2, const float* __restrict__ xsq,
    const unsigned* __restrict__ cand, const unsigned* __restrict__ counts,
    unsigned long long* __restrict__ bestKey) {
    extern __shared__ float csh[];          // [256][65] cb^T fp32
    const int tid = threadIdx.x;
    const int nb = blockIdx.x >> 2;         // 64-code block
    const int quarter = blockIdx.x & 3;
    int cnt = (int)counts[nb];
    if (cnt > CCAP) cnt = CCAP;
    if (quarter * 16 >= cnt) return;        // block-uniform, pre-staging

    // stage 64 cb rows transposed (coalesced reads; 8-way writes, one-time)
#pragma unroll
    for (int r = 0; r < 16; ++r) {
        int i = r * 256 + tid;
        int row = i >> 6, kq = i & 63;
        float4 v = reinterpret_cast<const float4*>(cb + (size_t)(nb * CBS + row) * D)[kq];
        csh[(kq * 4 + 0) * 65 + row] = v.x;
        csh[(kq * 4 + 1) * 65 + row] = v.y;
        csh[(kq * 4 + 2) * 65 + row] = v.z;
        csh[(kq * 4 + 3) * 65 + row] = v.w;
    }
    __syncthreads();                        // last barrier in this kernel

    const int w = tid >> 6, j = tid & 63;
    const float e2v = e2[nb * CBS + j];
    const int ci0 = nb * CBS + j;
    const float4* X4 = reinterpret_cast<const float4*>(x);
    const unsigned* clist = cand + (size_t)nb * CCAP;
    const int slot = quarter * 4 + w;       // 0..15 sweep slots per nb
    const int p0 = slot * 4;
    if (p0 >= cnt) return;                  // wave-uniform; no barriers follow

    for (int p = p0; p < cnt; p += 64) {
        int i1 = p + 1 < cnt ? p + 1 : cnt - 1;  // tail: replicate (idempotent)
        int i2 = p + 2 < cnt ? p + 2 : cnt - 1;
        int i3 = p + 3 < cnt ? p + 3 : cnt - 1;
        int t0 = (int)clist[p],  t1 = (int)clist[i1];
        int t2 = (int)clist[i2], t3 = (int)clist[i3];
        // lane j holds x[t][4j..4j+3]; coalesced, one load per candidate
        float4 v0 = X4[(size_t)t0 * 64 + j];
        float4 v1 = X4[(size_t)t1 * 64 + j];
        float4 v2 = X4[(size_t)t2 * 64 + j];
        float4 v3 = X4[(size_t)t3 * 64 + j];
        float a0 = 0.f, a1 = 0.f, a2 = 0.f, a3 = 0.f;
        // k ascending, ONE fma chain per (token, code) — bit-compat order.
        // x[t][k] = readlane(v.comp[k&3], k>>2): pure register broadcast.
#pragma unroll
        for (int kq = 0; kq < 64; ++kq) {
            float c0 = csh[(kq * 4 + 0) * 65 + j];
            float c1 = csh[(kq * 4 + 1) * 65 + j];
            float c2 = csh[(kq * 4 + 2) * 65 + j];
            float c3 = csh[(kq * 4 + 3) * 65 + j];
            a0 = fmaf(rdlane(v0.x, kq), c0, a0);
            a0 = fmaf(rdlane(v0.y, kq), c1, a0);
            a0 = fmaf(rdlane(v0.z, kq), c2, a0);
            a0 = fmaf(rdlane(v0.w, kq), c3, a0);
            a1 = fmaf(rdlane(v1.x, kq), c0, a1);
            a1 = fmaf(rdlane(v1.y, kq), c1, a1);
            a1 = fmaf(rdlane(v1.z, kq), c2, a1);
            a1 = fmaf(rdlane(v1.w, kq), c3, a1);
            a2 = fmaf(rdlane(v2.x, kq), c0, a2);
            a2 = fmaf(rdlane(v2.y, kq), c1, a2);
            a2 = fmaf(rdlane(v2.z, kq), c2, a2);
            a2 = fmaf(rdlane(v2.w, kq), c3, a2);
            a3 = fmaf(rdlane(v3.x, kq), c0, a3);
            a3 = fmaf(rdlane(v3.y, kq), c1, a3);
            a3 = fmaf(rdlane(v3.z, kq), c2, a3);
            a3 = fmaf(rdlane(v3.w, kq), c3, a3);
        }
        float av[4] = {a0, a1, a2, a3};
        int tv[4] = {t0, t1, t2, t3};
#pragma unroll
        for (int g = 0; g < 4; ++g) {
            float dd = fmaf(-2.f, av[g], xsq[tv[g]] + e2v);
            int ci = ci0;
#pragma unroll
            for (int off = 1; off < 64; off <<= 1) {
                float od = __shfl_xor(dd, off);
                int oc = __shfl_xor(ci, off);
                if (od < dd || (od == dd && oc < ci)) { dd = od; ci = oc; }
            }
            if (j == 0) {
                unsigned u = __float_as_uint(dd);
                u = (u & 0x80000000u) ? ~u : (u | 0x80000000u);
                unsigned long long key =
                    ((unsigned long long)u << 32) | (unsigned)ci;
                atomicMin(bestKey + tv[g], key);   // non-returning: no stall
            }
        }
    }
}

// ---- Pass 3: gather codebook row, emit quantized + idx + partial loss ----
__global__ __launch_bounds__(256) void gather_kernel(
    const float* __restrict__ x, const float* __restrict__ cb,
    const unsigned long long* __restrict__ bestKey,
    float* __restrict__ out, float* __restrict__ partial) {
    __shared__ float red[4];
    const int token = blockIdx.x;
    const int tid = threadIdx.x;
    int idx = (int)(bestKey[token] & 0xFFFFFFFFULL);
    if ((unsigned)idx >= (unsigned)KCODES) idx = 0;  // defensive: no OOB access
    float q = cb[(size_t)idx * D + tid];
    float xv = x[(size_t)token * D + tid];
    out[(size_t)token * D + tid] = q;
    float d = q - xv;
    d = d * d;
#pragma unroll
    for (int off = 32; off > 0; off >>= 1) d += __shfl_down(d, off);
    if ((tid & 63) == 0) red[tid >> 6] = d;
    __syncthreads();
    if (tid == 0) {
        partial[token] = red[0] + red[1] + red[2] + red[3];
        out[(size_t)QSIZE + token] = (float)idx;
    }
}

// 64 blocks, one element/thread; per-block reduce + one atomicAdd into the
// (pass2a-zeroed) loss slot. (Validated in R2: absmax unchanged.)
__global__ __launch_bounds__(256) void loss_kernel(const float* __restrict__ partial,
                                                   float* __restrict__ out) {
    __shared__ float red[4];
    int gid = blockIdx.x * 256 + threadIdx.x;
    float s = partial[gid];
#pragma unroll
    for (int off = 32; off > 0; off >>= 1) s += __shfl_down(s, off);
    if ((threadIdx.x & 63) == 0) red[threadIdx.x >> 6] = s;
    __syncthreads();
    if (threadIdx.x == 0) {
        float total = red[0] + red[1] + red[2] + red[3];
        atomicAdd(out + (size_t)QSIZE + NTOK, 0.25f * total / (float)QSIZE);
    }
}

extern "C" void kernel_launch(void* const* d_in, const int* in_sizes, int n_in,
                              void* d_out, int out_size, void* d_ws, size_t ws_size,
                              hipStream_t stream) {
    const float* x = (const float*)d_in[0];     // [16384, 256]
    const float* cb = (const float*)d_in[1];    // [8192, 256]
    float* out = (float*)d_out;
    float* ws = (float*)d_ws;

    // d_out scratch map (all regions dead before gather overwrites them):
    //   [0, 8M):   xb fp16 (pass1 in) -> cand u32 [128][4096] (2 MB; pass2a
    //              writes AFTER pass1 done; stream-ordered)
    //   [8M, 12M): bmin bf16 [NTOK][128]
    //   [12M,16M): cbb fp16
    ushort* xb = (ushort*)d_out;
    ushort* bmin = (ushort*)((char*)d_out + 8388608);
    ushort* cbb = (ushort*)((char*)d_out + 12582912);
    unsigned* cand = (unsigned*)d_out;

    // ws (floats): e2[8192] | xsq[16384] | counts u32[128] (in old rowmin
    // slot) | partial[16384] @ +8192+2*16384 | bestKey u64 @ +8192+3*16384
    float* e2 = ws;
    float* xsq = ws + 8192;
    unsigned* counts = (unsigned*)(ws + 8192 + 16384);
    float* partial = ws + 8192 + 2 * 16384;
    unsigned long long* bestKey = (unsigned long long*)(ws + 8192 + 3 * 16384);

    hipFuncSetAttribute((const void*)pass2b_kernel,
                        hipFuncAttributeMaxDynamicSharedMemorySize, P2_LDS);

    cvtx_kernel<<<QSIZE / 1024, 256, 0, stream>>>(x, xb, xsq);
    cvtc_kernel<<<KCODES * D / 1024, 256, 0, stream>>>(cb, cbb, e2);
    pass1_kernel<<<dim3(NTOK / 128, KCODES / 128), 256, 0, stream>>>(xb, cbb, e2, bmin);
    hipMemsetAsync(counts, 0, NBLK * sizeof(unsigned), stream);
    pass2a_kernel<<<NTOK / 256, 256, 0, stream>>>(bmin, bestKey, cand, counts, out);
    pass2b_kernel<<<4 * NBLK, 256, P2_LDS, stream>>>(
        x, cb, e2, xsq, cand, counts, bestKey);
    gather_kernel<<<NTOK, 256, 0, stream>>>(x, cb, bestKey, out, partial);
    loss_kernel<<<NTOK / 256, 256, 0, stream>>>(partial, out);
}

// Round 4
// 354.055 us; speedup vs baseline: 2.4783x; 1.3098x over previous
//
#include <hip/hip_runtime.h>

#define D 256
#define KCODES 8192
#define NTOK 16384
#define QSIZE (NTOK * D)
#define NBLK 128              // screening blocks of 64 codes
#define CBS 64
// TH: candidate window. Budget (fp16 screen, cb pre-scaled 2^12 so no fp16
// subnormals): ref-rounding eta <= 3.05e-5 + 2*fp16-dot err (max-stat) ~2.4e-5
// + bf16 quantization ~3e-5 => delta ~5.9e-5, need TH >= 2*delta ~1.2e-4.
// TH = 2e-4 gives ~1.7x margin. Used identically for (a) block flagging
// (true-argmin block must be flagged: needs TH >= 2*delta) and (b) the NEW
// decided-gap test (screened gap > TH => true argmin == screened argmin:
// needs the same TH >= 2*delta). Ties give gap 0 -> always rescanned.
#define TH 2e-4f
#define CBSCALE 4096.0f       // exact pow2; acc = 2^12 * dot
#define UNSCALE2 4.8828125e-4f // 2^-11 = 2 * 2^-12 (exact)
#define CCAP 4096             // per-nb candidate capacity (need ~40 now)

typedef _Float16 f16x8 __attribute__((ext_vector_type(8)));  // 8 fp16, 4 VGPRs
typedef float f32x4 __attribute__((ext_vector_type(4)));
typedef __attribute__((address_space(3))) void* lds_vp;
typedef __attribute__((address_space(1))) const void* gbl_vp;

#define P2_LDS (256 * 65 * 4)           // 66560 B: cb^T fp32 [256][65] ONLY

__device__ __forceinline__ ushort f32_to_bf16(float f) {
    unsigned u = __float_as_uint(f);
    return (ushort)((u + 0x7FFFu + ((u >> 16) & 1)) >> 16);
}
__device__ __forceinline__ float bf16_to_f32(ushort h) {
    return __uint_as_float((unsigned)h << 16);
}
__device__ __forceinline__ ushort f32_to_f16(float f) {
    _Float16 h = (_Float16)f;          // v_cvt_f16_f32, RNE
    ushort u; __builtin_memcpy(&u, &h, 2);
    return u;
}
// race-free broadcast: v_readlane_b32 (register file, exec-independent)
__device__ __forceinline__ float rdlane(float v, int lane) {
    return __uint_as_float(__builtin_amdgcn_readlane(__float_as_uint(v), lane));
}

// ---- fused: x -> fp16 + row ||x||^2 (same values/order as before) ----
__global__ __launch_bounds__(256) void cvtx_kernel(const float* __restrict__ x,
                                                   ushort* __restrict__ xb,
                                                   float* __restrict__ xsq) {
    int i = blockIdx.x * 256 + threadIdx.x;      // float4 index
    float4 v = reinterpret_cast<const float4*>(x)[i];
    ushort4 o;
    o.x = f32_to_f16(v.x); o.y = f32_to_f16(v.y);
    o.z = f32_to_f16(v.z); o.w = f32_to_f16(v.w);
    reinterpret_cast<ushort4*>(xb)[i] = o;
    float s = v.x * v.x + v.y * v.y + v.z * v.z + v.w * v.w;
#pragma unroll
    for (int off = 32; off > 0; off >>= 1) s += __shfl_down(s, off);
    if ((threadIdx.x & 63) == 0) xsq[i >> 6] = s;
}

// ---- e2[c] = sum(cb[c,:]^2) fp32 exact; one wave per row (R0-proven) ----
__global__ __launch_bounds__(256) void e2_kernel(const float* __restrict__ cb,
                                                 float* __restrict__ e2) {
    int c = blockIdx.x * 4 + (threadIdx.x >> 6);
    int lane = threadIdx.x & 63;
    float4 v = reinterpret_cast<const float4*>(cb + (size_t)c * D)[lane];
    float s = v.x * v.x + v.y * v.y + v.z * v.z + v.w * v.w;
#pragma unroll
    for (int off = 32; off > 0; off >>= 1) s += __shfl_down(s, off);
    if (lane == 0) e2[c] = s;
}

// ---- Pass 1: fp16 MFMA screening GEMM + top-2/argmin epilogue ----
// A staged via global_load_lds from xb (unchanged). B converted IN-KERNEL
// from cb fp32 (reg-staged: load->cvt(v*CBSCALE, RNE)->ds_write) — same ops
// per element as the old cvtc kernel => identical fp16 bits => identical
// MFMA fragments and acc values (8 chained 16x16x32 ascending kt, R3 order).
// NEW epilogue: per (token, 64-block) within-block top-2 + argmin, packed:
//   screen = m1_bf16<<16 | arg6<<1 | (m2 - m1 > TH).
__global__ __launch_bounds__(256, 3) void pass1_kernel(
    const ushort* __restrict__ xb, const float* __restrict__ cb,
    const float* __restrict__ e2, unsigned* __restrict__ screen) {
    __shared__ ushort ash[2][128 * 32];
    __shared__ ushort bsh[2][128 * 32];
    const int tid = threadIdx.x;
    const int w = tid >> 6, l = tid & 63;
    const int wr = w >> 1, wc = w & 1;
    const int t0 = blockIdx.x * 128, n0 = blockIdx.y * 128;

    f32x4 acc[4][4];
#pragma unroll
    for (int mt = 0; mt < 4; ++mt)
#pragma unroll
        for (int nt = 0; nt < 4; ++nt) acc[mt][nt] = (f32x4)0.f;

    // A: wave w stages LDS bytes [w*2048,(w+1)*2048) via two 1 KB wave-loads.
    const int byte0 = w * 2048 + l * 16;
    const int row0 = byte0 >> 6, c80 = (byte0 >> 4) & 3;
    const int byte1 = byte0 + 1024;
    const int row1 = byte1 >> 6, c81 = (byte1 >> 4) & 3;
    const ushort* ga0 = xb + (size_t)(t0 + row0) * D + c80 * 8;
    const ushort* ga1 = xb + (size_t)(t0 + row1) * D + c81 * 8;
    // B: thread covers row=tid>>1, k-half=(tid&1)*16 of the [128][32] tile.
    const int brow = tid >> 1, bkh = (tid & 1) * 16;
    const float* gB = cb + (size_t)(n0 + brow) * D + bkh;
    float4 rb[4];

#define STAGE_A(KT, BUF)                                                                   \
    do {                                                                                   \
        __builtin_amdgcn_global_load_lds((gbl_vp)(ga0 + (KT) * 32),                        \
                                         (lds_vp)(&ash[BUF][w * 1024]), 16, 0, 0);         \
        __builtin_amdgcn_global_load_lds((gbl_vp)(ga1 + (KT) * 32),                        \
                                         (lds_vp)(&ash[BUF][w * 1024 + 512]), 16, 0, 0);   \
    } while (0)
#define LOAD_B(KT)                                                                         \
    do {                                                                                   \
        const float4* p = reinterpret_cast<const float4*>(gB + (KT) * 32);                 \
        rb[0] = p[0]; rb[1] = p[1]; rb[2] = p[2]; rb[3] = p[3];                            \
    } while (0)
#define WRITE_B(BUF)                                                                       \
    do {                                                                                   \
        unsigned q[8];                                                                     \
        _Pragma("unroll")                                                                  \
        for (int e = 0; e < 4; ++e) {                                                      \
            q[2 * e] = (unsigned)f32_to_f16(rb[e].x * CBSCALE) |                           \
                       ((unsigned)f32_to_f16(rb[e].y * CBSCALE) << 16);                    \
            q[2 * e + 1] = (unsigned)f32_to_f16(rb[e].z * CBSCALE) |                       \
                           ((unsigned)f32_to_f16(rb[e].w * CBSCALE) << 16);                \
        }                                                                                  \
        uint4* dst = reinterpret_cast<uint4*>(&bsh[BUF][brow * 32 + bkh]);                 \
        uint4 q0; q0.x = q[0]; q0.y = q[1]; q0.z = q[2]; q0.w = q[3];                      \
        uint4 q1; q1.x = q[4]; q1.y = q[5]; q1.z = q[6]; q1.w = q[7];                      \
        dst[0] = q0; dst[1] = q1;                                                          \
    } while (0)

    LOAD_B(0);
    STAGE_A(0, 0);
    WRITE_B(0);
    __syncthreads();                    // drains vmcnt(0)+lgkm: buf0 ready
#pragma unroll
    for (int kt = 0; kt < 8; ++kt) {
        const int cur = kt & 1;
        if (kt < 7) { LOAD_B(kt + 1); STAGE_A(kt + 1, cur ^ 1); }
        const ushort* xbase = &ash[cur][0] + (wr * 64 + (l & 15)) * 32 + (l >> 4) * 8;
        const ushort* cbase = &bsh[cur][0] + (wc * 64 + (l & 15)) * 32 + (l >> 4) * 8;
        f16x8 a[4], b[4];
#pragma unroll
        for (int mt = 0; mt < 4; ++mt)
            a[mt] = *reinterpret_cast<const f16x8*>(xbase + mt * 16 * 32);
#pragma unroll
        for (int nt = 0; nt < 4; ++nt)
            b[nt] = *reinterpret_cast<const f16x8*>(cbase + nt * 16 * 32);
#pragma unroll
        for (int mt = 0; mt < 4; ++mt)
#pragma unroll
            for (int nt = 0; nt < 4; ++nt)
                acc[mt][nt] = __builtin_amdgcn_mfma_f32_16x16x32_f16(
                    a[mt], b[nt], acc[mt][nt], 0, 0, 0);
        if (kt < 7) WRITE_B(cur ^ 1);
        __syncthreads();                // prefetch drained + buf reuse-safe
    }
#undef STAGE_A
#undef LOAD_B
#undef WRITE_B

    float e2v[4];
#pragma unroll
    for (int nt = 0; nt < 4; ++nt)
        e2v[nt] = e2[n0 + wc * 64 + nt * 16 + (l & 15)];
    const int nb64 = blockIdx.y * 2 + wc;
#pragma unroll
    for (int mt = 0; mt < 4; ++mt) {
#pragma unroll
        for (int r = 0; r < 4; ++r) {
            // within-block top-2 with argmin; dm values bit-identical to R3's
            float v1 = fmaf(-UNSCALE2, acc[mt][0][r], e2v[0]);
            float v2 = 3.4e38f;
            int a1 = (l & 15);
#pragma unroll
            for (int nt = 1; nt < 4; ++nt) {
                float f = fmaf(-UNSCALE2, acc[mt][nt][r], e2v[nt]);
                int idx = nt * 16 + (l & 15);
                bool lt = f < v1;
                v2 = lt ? v1 : fminf(v2, f);
                a1 = lt ? idx : a1;
                v1 = lt ? f : v1;
            }
#pragma unroll
            for (int off = 1; off < 16; off <<= 1) {
                float ov1 = __shfl_xor(v1, off);
                float ov2 = __shfl_xor(v2, off);
                int oa1 = __shfl_xor(a1, off);
                float nv2 = fminf(fminf(v2, ov2), fmaxf(v1, ov1));
                bool take = ov1 < v1;      // tie -> keep own; v2==v1 -> rescan
                v1 = take ? ov1 : v1;
                a1 = take ? oa1 : a1;
                v2 = nv2;
            }
            if ((l & 15) == 0) {
                int token = t0 + wr * 64 + mt * 16 + (l >> 4) * 4 + r;
                ushort m1b = f32_to_bf16(v1);
                unsigned big = (v2 - bf16_to_f32(m1b) > TH) ? 1u : 0u;
                screen[(size_t)token * NBLK + nb64] =
                    ((unsigned)m1b << 16) | ((unsigned)a1 << 1) | big;
            }
        }
    }
}

// ---- Pass 2a: wave-per-token global top-2 over 128 block-mins ----
// Coalesced (wave reads its token's 512 B row). Decided tokens (cross-block
// gap > TH AND within-block big-bit) write bestKey = argmin directly and
// skip rescan entirely. Ambiguous tokens: append to per-nb candidate lists
// (same flag criterion m1[b] <= m1* + TH as all prior rounds).
__global__ __launch_bounds__(256) void pass2a_kernel(
    const unsigned* __restrict__ screen, unsigned long long* __restrict__ bestKey,
    unsigned* __restrict__ cand, unsigned* __restrict__ counts,
    float* __restrict__ out) {
    const int tid = threadIdx.x;
    const int w = tid >> 6, l = tid & 63;
    const int token = blockIdx.x * 4 + w;
    if (blockIdx.x == 0 && tid == 0) out[(size_t)QSIZE + NTOK] = 0.f;

    uint2 u2 = reinterpret_cast<const uint2*>(screen + (size_t)token * NBLK)[l];
    float ma = bf16_to_f32((ushort)(u2.x >> 16));
    float mb = bf16_to_f32((ushort)(u2.y >> 16));
    float v1, v2; unsigned pk; int blk;
    if (mb < ma) { v1 = mb; v2 = ma; pk = u2.y; blk = 2 * l + 1; }
    else         { v1 = ma; v2 = mb; pk = u2.x; blk = 2 * l; }
#pragma unroll
    for (int off = 1; off < 64; off <<= 1) {
        float ov1 = __shfl_xor(v1, off);
        float ov2 = __shfl_xor(v2, off);
        unsigned opk = __shfl_xor(pk, off);
        int oblk = __shfl_xor(blk, off);
        float nv2 = fminf(fminf(v2, ov2), fmaxf(v1, ov1));
        bool take = ov1 < v1;              // tie -> v2==v1 -> undecided
        v1 = take ? ov1 : v1;
        pk = take ? opk : pk;
        blk = take ? oblk : blk;
        v2 = nv2;
    }
    // butterfly: all lanes hold identical (v1, v2, pk, blk)
    bool decided = ((pk & 1u) != 0u) && (v2 - v1 > TH);
    if (l == 0)
        bestKey[token] = decided
            ? (unsigned long long)(unsigned)(blk * 64 + (int)((pk >> 1) & 63u))
            : 0xFFFFFFFFFFFFFFFFULL;
    if (!decided) {
        float thr = v1 + TH;
        if (ma <= thr) {
            unsigned s = atomicAdd(&counts[2 * l], 1u);
            if (s < CCAP) cand[(size_t)(2 * l) * CCAP + s] = (unsigned)token;
        }
        if (mb <= thr) {
            unsigned s = atomicAdd(&counts[2 * l + 1], 1u);
            if (s < CCAP) cand[(size_t)(2 * l + 1) * CCAP + s] = (unsigned)token;
        }
    }
}

// ---- Pass 2b: exact fp32-chain rescan of compacted candidates ----
// R3 VERBATIM (proven: VGPR 128, no spill, passed). Single sequential fma
// chain k=0..255 per (token, code), v_readlane broadcast, d = fl(fl(xsq+e2)
// - 2*dot), shfl-xor tie-break (smallest index), packed-key atomicMin.
// Workload now ~4x smaller (ambiguous tokens only).
__global__ __launch_bounds__(256, 2) void pass2b_kernel(
    const float* __restrict__ x, const float* __restrict__ cb,
    const float* __restrict__ e2, const float* __restrict__ xsq,
    const unsigned* __restrict__ cand, const unsigned* __restrict__ counts,
    unsigned long long* __restrict__ bestKey) {
    extern __shared__ float csh[];          // [256][65] cb^T fp32
    const int tid = threadIdx.x;
    const int nb = blockIdx.x >> 2;         // 64-code block
    const int quarter = blockIdx.x & 3;
    int cnt = (int)counts[nb];
    if (cnt > CCAP) cnt = CCAP;
    if (quarter * 16 >= cnt) return;        // block-uniform, pre-staging

    // stage 64 cb rows transposed (coalesced reads; 8-way writes, one-time)
#pragma unroll
    for (int r = 0; r < 16; ++r) {
        int i = r * 256 + tid;
        int row = i >> 6, kq = i & 63;
        float4 v = reinterpret_cast<const float4*>(cb + (size_t)(nb * CBS + row) * D)[kq];
        csh[(kq * 4 + 0) * 65 + row] = v.x;
        csh[(kq * 4 + 1) * 65 + row] = v.y;
        csh[(kq * 4 + 2) * 65 + row] = v.z;
        csh[(kq * 4 + 3) * 65 + row] = v.w;
    }
    __syncthreads();                        // last barrier in this kernel

    const int w = tid >> 6, j = tid & 63;
    const float e2v = e2[nb * CBS + j];
    const int ci0 = nb * CBS + j;
    const float4* X4 = reinterpret_cast<const float4*>(x);
    const unsigned* clist = cand + (size_t)nb * CCAP;
    const int slot = quarter * 4 + w;       // 0..15 sweep slots per nb
    const int p0 = slot * 4;
    if (p0 >= cnt) return;                  // wave-uniform; no barriers follow

    for (int p = p0; p < cnt; p += 64) {
        int i1 = p + 1 < cnt ? p + 1 : cnt - 1;  // tail: replicate (idempotent)
        int i2 = p + 2 < cnt ? p + 2 : cnt - 1;
        int i3 = p + 3 < cnt ? p + 3 : cnt - 1;
        int t0 = (int)clist[p],  t1 = (int)clist[i1];
        int t2 = (int)clist[i2], t3 = (int)clist[i3];
        // lane j holds x[t][4j..4j+3]; coalesced, one load per candidate
        float4 v0 = X4[(size_t)t0 * 64 + j];
        float4 v1 = X4[(size_t)t1 * 64 + j];
        float4 v2 = X4[(size_t)t2 * 64 + j];
        float4 v3 = X4[(size_t)t3 * 64 + j];
        float a0 = 0.f, a1 = 0.f, a2 = 0.f, a3 = 0.f;
        // k ascending, ONE fma chain per (token, code) — bit-compat order.
        // x[t][k] = readlane(v.comp[k&3], k>>2): pure register broadcast.
#pragma unroll
        for (int kq = 0; kq < 64; ++kq) {
            float c0 = csh[(kq * 4 + 0) * 65 + j];
            float c1 = csh[(kq * 4 + 1) * 65 + j];
            float c2 = csh[(kq * 4 + 2) * 65 + j];
            float c3 = csh[(kq * 4 + 3) * 65 + j];
            a0 = fmaf(rdlane(v0.x, kq), c0, a0);
            a0 = fmaf(rdlane(v0.y, kq), c1, a0);
            a0 = fmaf(rdlane(v0.z, kq), c2, a0);
            a0 = fmaf(rdlane(v0.w, kq), c3, a0);
            a1 = fmaf(rdlane(v1.x, kq), c0, a1);
            a1 = fmaf(rdlane(v1.y, kq), c1, a1);
            a1 = fmaf(rdlane(v1.z, kq), c2, a1);
            a1 = fmaf(rdlane(v1.w, kq), c3, a1);
            a2 = fmaf(rdlane(v2.x, kq), c0, a2);
            a2 = fmaf(rdlane(v2.y, kq), c1, a2);
            a2 = fmaf(rdlane(v2.z, kq), c2, a2);
            a2 = fmaf(rdlane(v2.w, kq), c3, a2);
            a3 = fmaf(rdlane(v3.x, kq), c0, a3);
            a3 = fmaf(rdlane(v3.y, kq), c1, a3);
            a3 = fmaf(rdlane(v3.z, kq), c2, a3);
            a3 = fmaf(rdlane(v3.w, kq), c3, a3);
        }
        float av[4] = {a0, a1, a2, a3};
        int tv[4] = {t0, t1, t2, t3};
#pragma unroll
        for (int g = 0; g < 4; ++g) {
            float dd = fmaf(-2.f, av[g], xsq[tv[g]] + e2v);
            int ci = ci0;
#pragma unroll
            for (int off = 1; off < 64; off <<= 1) {
                float od = __shfl_xor(dd, off);
                int oc = __shfl_xor(ci, off);
                if (od < dd || (od == dd && oc < ci)) { dd = od; ci = oc; }
            }
            if (j == 0) {
                unsigned u = __float_as_uint(dd);
                u = (u & 0x80000000u) ? ~u : (u | 0x80000000u);
                unsigned long long key =
                    ((unsigned long long)u << 32) | (unsigned)ci;
                atomicMin(bestKey + tv[g], key);   // non-returning: no stall
            }
        }
    }
}

// ---- Pass 3: gather codebook row, emit quantized + idx + partial loss ----
__global__ __launch_bounds__(256) void gather_kernel(
    const float* __restrict__ x, const float* __restrict__ cb,
    const unsigned long long* __restrict__ bestKey,
    float* __restrict__ out, float* __restrict__ partial) {
    __shared__ float red[4];
    const int token = blockIdx.x;
    const int tid = threadIdx.x;
    int idx = (int)(bestKey[token] & 0xFFFFFFFFULL);
    if ((unsigned)idx >= (unsigned)KCODES) idx = 0;  // defensive: no OOB access
    float q = cb[(size_t)idx * D + tid];
    float xv = x[(size_t)token * D + tid];
    out[(size_t)token * D + tid] = q;
    float d = q - xv;
    d = d * d;
#pragma unroll
    for (int off = 32; off > 0; off >>= 1) d += __shfl_down(d, off);
    if ((tid & 63) == 0) red[tid >> 6] = d;
    __syncthreads();
    if (tid == 0) {
        partial[token] = red[0] + red[1] + red[2] + red[3];
        out[(size_t)QSIZE + token] = (float)idx;
    }
}

// 64 blocks, one element/thread; per-block reduce + one atomicAdd into the
// (pass2a-zeroed) loss slot. (Validated R2/R3: absmax unchanged.)
__global__ __launch_bounds__(256) void loss_kernel(const float* __restrict__ partial,
                                                   float* __restrict__ out) {
    __shared__ float red[4];
    int gid = blockIdx.x * 256 + threadIdx.x;
    float s = partial[gid];
#pragma unroll
    for (int off = 32; off > 0; off >>= 1) s += __shfl_down(s, off);
    if ((threadIdx.x & 63) == 0) red[threadIdx.x >> 6] = s;
    __syncthreads();
    if (threadIdx.x == 0) {
        float total = red[0] + red[1] + red[2] + red[3];
        atomicAdd(out + (size_t)QSIZE + NTOK, 0.25f * total / (float)QSIZE);
    }
}

extern "C" void kernel_launch(void* const* d_in, const int* in_sizes, int n_in,
                              void* d_out, int out_size, void* d_ws, size_t ws_size,
                              hipStream_t stream) {
    const float* x = (const float*)d_in[0];     // [16384, 256]
    const float* cb = (const float*)d_in[1];    // [8192, 256]
    float* out = (float*)d_out;
    float* ws = (float*)d_ws;

    // d_out scratch map (all regions dead before gather overwrites them):
    //   [0, 8M):  xb fp16 (pass1 A-in) -> cand u32 [128][4096] (2 MB; pass2a
    //             writes AFTER pass1 done; stream-ordered)
    //   [8M,16M): screen u32 [NTOK][128] (pass1 out, pass2a in)
    ushort* xb = (ushort*)d_out;
    unsigned* screen = (unsigned*)((char*)d_out + 8388608);
    unsigned* cand = (unsigned*)d_out;

    // ws (floats): e2[8192] | xsq[16384] | counts u32[128] | partial[16384]
    //              @ +8192+2*16384 | bestKey u64 @ +8192+3*16384
    float* e2 = ws;
    float* xsq = ws + 8192;
    unsigned* counts = (unsigned*)(ws + 8192 + 16384);
    float* partial = ws + 8192 + 2 * 16384;
    unsigned long long* bestKey = (unsigned long long*)(ws + 8192 + 3 * 16384);

    hipFuncSetAttribute((const void*)pass2b_kernel,
                        hipFuncAttributeMaxDynamicSharedMemorySize, P2_LDS);

    cvtx_kernel<<<QSIZE / 1024, 256, 0, stream>>>(x, xb, xsq);
    e2_kernel<<<KCODES / 4, 256, 0, stream>>>(cb, e2);
    pass1_kernel<<<dim3(NTOK / 128, KCODES / 128), 256, 0, stream>>>(xb, cb, e2, screen);
    hipMemsetAsync(counts, 0, NBLK * sizeof(unsigned), stream);
    pass2a_kernel<<<NTOK / 4, 256, 0, stream>>>(screen, bestKey, cand, counts, out);
    pass2b_kernel<<<4 * NBLK, 256, P2_LDS, stream>>>(
        x, cb, e2, xsq, cand, counts, bestKey);
    gather_kernel<<<NTOK, 256, 0, stream>>>(x, cb, bestKey, out, partial);
    loss_kernel<<<NTOK / 256, 256, 0, stream>>>(partial, out);
}